// Round 5
// baseline (275.263 us; speedup 1.0000x reference)
//
#include <hip/hip_runtime.h>
#include <stdint.h>

#define GAS __attribute__((address_space(1)))
#define LAS __attribute__((address_space(3)))

typedef unsigned short u16;
typedef __attribute__((ext_vector_type(8))) __bf16 bf16x8;
typedef __attribute__((ext_vector_type(4))) float f32x4;
typedef __attribute__((ext_vector_type(4))) unsigned short u16x4;
typedef __attribute__((ext_vector_type(8))) unsigned short u16x8;

#define SEQ 2048
#define WORD 1024
#define EMBED 128
#define NHEAD 16

__device__ __forceinline__ u16 f2b(float f) {
  return __builtin_bit_cast(u16, (__bf16)f);
}

// fragment-major offsets (within one head) ------------------------------
// Q: attn reads qf[rs][kc] at lane l: qrow = qb*64+rs*16+ln, e = kc*32+quad*8+j
__device__ __forceinline__ long qfrag_off(int qrow, int e) {
  return ((((long)(qrow >> 4)) * 4 + (e >> 5)) * 64 + ((e >> 3) & 3) * 16 +
          (qrow & 15)) * 8 + (e & 7);
}
// V: attn reads vf[es] at lane l: er = es*16+ln, key = sup*128+wk*32+quad*8+j
__device__ __forceinline__ long vfrag_off(int er, int key) {
  return (((((long)(key >> 7)) * 4 + ((key >> 5) & 3)) * 8 + (er >> 4)) * 64 +
          ((key >> 3) & 3) * 16 + (er & 15)) * 8 + (key & 7);
}

// ---------------- cast x (fp32 -> bf16), 4 elems/thread ----------------
__global__ __launch_bounds__(256) void cast_x_kernel(const float* __restrict__ x,
                                                     u16* __restrict__ xb) {
  int i = (blockIdx.x * 256 + threadIdx.x) * 4;
  float4 v = *(const float4*)(x + i);
  ushort4 o;
  o.x = f2b(v.x); o.y = f2b(v.y); o.z = f2b(v.z); o.w = f2b(v.w);
  *(ushort4*)(xb + i) = o;
}

// ------------- transpose+cast: src[R][C] fp32 -> dst[C][R] bf16 --------
__global__ __launch_bounds__(256) void transpose_cast_kernel(
    const float* __restrict__ s0, const float* __restrict__ s1,
    const float* __restrict__ s2, u16* __restrict__ d0, u16* __restrict__ d1,
    u16* __restrict__ d2, int R, int C, long stride, int zsel) {
  __shared__ float tile[32][33];
  const float* s;
  u16* d;
  if (zsel) {
    int z = blockIdx.z;
    int wsel = z >> 4, hh = z & 15;
    s = (wsel == 0 ? s0 : wsel == 1 ? s1 : s2) + (long)hh * stride;
    d = (wsel == 0 ? d0 : wsel == 1 ? d1 : d2) + (long)hh * stride;
  } else {
    s = s0; d = d0;
  }
  int r0 = blockIdx.x * 32, c0 = blockIdx.y * 32;
  int tx = threadIdx.x & 31, ty = threadIdx.x >> 5;
#pragma unroll
  for (int i = 0; i < 4; ++i)
    tile[ty + i * 8][tx] = s[(long)(r0 + ty + i * 8) * C + c0 + tx];
  __syncthreads();
#pragma unroll
  for (int i = 0; i < 4; ++i)
    d[(long)(c0 + ty + i * 8) * R + r0 + tx] = f2b(tile[tx][ty + i * 8]);
}

// ---------------- generic 128x128-tile GEMM: C = (A·B^T + bias) * scale ----
// mode: 0 = fp32 linear, 1 = u16 linear, 2 = u16 Q-fragment-major,
//       3 = u16 V-fragment-major. For modes 2/3 dst is the head base and
//       rowbase/colbase give global (row,col) of the tile.
template <int MODE>
__device__ __forceinline__ void gemm128(const u16* __restrict__ A, const u16* __restrict__ B,
                                        void* __restrict__ Cp, int lda, int ldb, int ldc,
                                        int ksteps, const float* biasN, const float* biasM,
                                        float scale, int rowbase, int colbase) {
  __shared__ u16 lA[128 * 64];
  __shared__ u16 lB[128 * 64];
  const int tid = threadIdx.x;
  const int l = tid & 63, w = tid >> 6;
  const int quad = l >> 4, ln = l & 15;
  const int wm = w >> 1, wn = w & 1;
  f32x4 acc[4][4] = {};
  for (int ks = 0; ks < ksteps; ++ks) {
    const u16* Ak = A + ks * 64;
    const u16* Bk = B + ks * 64;
    __syncthreads();
#pragma unroll
    for (int i = 0; i < 4; ++i) {
      int idx = w * 256 + i * 64 + l;
      int r = idx >> 3, cp = idx & 7;
      int cg = cp ^ (r & 7);
      __builtin_amdgcn_global_load_lds((const GAS void*)(Ak + (long)r * lda + cg * 8),
                                       (LAS void*)(lA + (w * 256 + i * 64) * 8), 16, 0, 0);
      __builtin_amdgcn_global_load_lds((const GAS void*)(Bk + (long)r * ldb + cg * 8),
                                       (LAS void*)(lB + (w * 256 + i * 64) * 8), 16, 0, 0);
    }
    __syncthreads();
    bf16x8 af[2][4], bfv[2][4];
#pragma unroll
    for (int kc = 0; kc < 2; ++kc) {
#pragma unroll
      for (int i = 0; i < 4; ++i) {
        int c = kc * 4 + quad;
        int rm = wm * 64 + i * 16 + ln;
        af[kc][i] = *(const bf16x8*)(lA + rm * 64 + ((c ^ (rm & 7)) * 8));
        int rn = wn * 64 + i * 16 + ln;
        bfv[kc][i] = *(const bf16x8*)(lB + rn * 64 + ((c ^ (rn & 7)) * 8));
      }
    }
#pragma unroll
    for (int kc = 0; kc < 2; ++kc)
#pragma unroll
      for (int i = 0; i < 4; ++i)
#pragma unroll
        for (int j = 0; j < 4; ++j)
          acc[i][j] = __builtin_amdgcn_mfma_f32_16x16x32_bf16(af[kc][i], bfv[kc][j],
                                                              acc[i][j], 0, 0, 0);
  }
#pragma unroll
  for (int i = 0; i < 4; ++i) {
#pragma unroll
    for (int j = 0; j < 4; ++j) {
      int row0 = wm * 64 + i * 16 + quad * 4;
      int col = wn * 64 + j * 16 + ln;
      float bn = biasN ? biasN[col] : 0.f;
#pragma unroll
      for (int reg = 0; reg < 4; ++reg) {
        int row = row0 + reg;
        float bm = biasM ? biasM[row] : 0.f;
        float v = (acc[i][j][reg] + bn + bm) * scale;
        if constexpr (MODE == 0) {
          ((float*)Cp)[(long)row * ldc + col] = v;
        } else if constexpr (MODE == 1) {
          ((u16*)Cp)[(long)row * ldc + col] = f2b(v);
        } else if constexpr (MODE == 2) {
          ((u16*)Cp)[qfrag_off(rowbase + row, colbase + col)] = f2b(v);
        } else {
          ((u16*)Cp)[vfrag_off(rowbase + row, colbase + col)] = f2b(v);
        }
      }
    }
  }
}

// ---------------- fused QKV projection (z: 0=Q,1=K,2=V^T) ----------------
// Q gets log2(e)/sqrt(E) folded in; Q and V are written fragment-major.
__global__ __launch_bounds__(256, 3) void qkv_gemm_kernel(
    const u16* __restrict__ xb, const u16* __restrict__ Wqt, const u16* __restrict__ Wkt,
    const u16* __restrict__ Wvt, const float* __restrict__ bq, const float* __restrict__ bk,
    const float* __restrict__ bv, u16* __restrict__ Qf, u16* __restrict__ Km,
    u16* __restrict__ Vf) {
  const int t = blockIdx.x;
  const int h = blockIdx.y;
  const int which = blockIdx.z;
  const float qscale = 0.12753042123789493f;  // log2(e)/sqrt(128)
  if (which == 0) {
    gemm128<2>(xb + t * 128 * WORD, Wqt + h * EMBED * WORD,
               Qf + (long)h * 262144, WORD, WORD, 0,
               WORD / 64, bq + h * EMBED, nullptr, qscale, t * 128, 0);
  } else if (which == 1) {
    gemm128<1>(xb + t * 128 * WORD, Wkt + h * EMBED * WORD,
               Km + (long)h * SEQ * EMBED + t * 128 * EMBED, WORD, WORD, EMBED,
               WORD / 64, bk + h * EMBED, nullptr, 1.f, 0, 0);
  } else {
    // V^T[e][s] = sum_w Wvt[h][e][w] * x[s][w]; rows = e, cols = keys
    gemm128<3>(Wvt + h * EMBED * WORD, xb + t * 128 * WORD,
               Vf + (long)h * 262144, WORD, WORD, 0,
               WORD / 64, nullptr, bv + h * EMBED, 1.f, 0, t * 128);
  }
}

// ---------------- flash attention, no-max softmax, S^T formulation --------
// block = 256 thr = 4 waves, ALL covering the same 64 q-rows (qb), 4-way
// key split (wave wk handles keys wk*32..+31 of each 128-key superiter).
// grid 32 x 16 = 512 blocks; LDS = 64K (K double-buffer) + 16K (P) = 80 KB
// -> 2 blocks/CU = 8 waves/CU (the r4 fix). K staged via global_load_lds,
// prefetch issued right after the barrier (flies across full compute
// phase). V and Q are read as fragment-major coalesced global loads (L2).
// S^T = K.Q^T (operand swap) puts 4 CONSECUTIVE keys per lane -> P is
// written with ds_write_b64 (8/sup) instead of 32 scalar u16 stores, and
// read back as b64 pairs (XOR chunk swizzle, wave-private, no barrier).
__global__ __launch_bounds__(256, 2) void attn_kernel(const u16* __restrict__ Qf,
                                                      const u16* __restrict__ Km,
                                                      const u16* __restrict__ Vf,
                                                      u16* __restrict__ Zs) {
  __shared__ u16 lK[2][16384];    // [buf][128 keys x 16 swizzled 16B chunks]
  __shared__ u16 lP[4][64 * 32];  // per-wave P [64 qrows][32 keys], b64-swizzled
  const int h = blockIdx.y, qb = blockIdx.x;  // qb: 64-row q tile, 0..31
  const int tid = threadIdx.x;
  const int l = tid & 63, wk = tid >> 6, quad = l >> 4, ln = l & 15;
  const u16* Kh = Km + (long)h * SEQ * EMBED;
  const u16* Qfh = Qf + (long)h * 262144;
  const u16* Vfh = Vf + (long)h * 262144;
  u16* Pw = lP[wk];

  // persistent Q fragments (coalesced fragment-major loads, once)
  bf16x8 qf[4][4];
#pragma unroll
  for (int rs = 0; rs < 4; ++rs)
#pragma unroll
    for (int kc = 0; kc < 4; ++kc)
      qf[rs][kc] = *(const bf16x8*)(Qfh + (((qb * 4 + rs) * 4 + kc) * 64 + l) * 8);

  const __bf16 ov = (ln == 0) ? (__bf16)1.0f : (__bf16)0.0f;
  const bf16x8 onesf = {ov, ov, ov, ov, ov, ov, ov, ov};

  f32x4 oacc[4][8] = {};
  f32x4 lacc[4] = {};

  auto stage = [&](int sup, int buf) {
#pragma unroll
    for (int j = 0; j < 8; ++j) {
      int cb = (j * 4 + wk) * 64;  // wave-uniform chunk base
      int c = cb + l;
      int kr = c >> 4, cg = (c & 15) ^ (kr & 15);
      __builtin_amdgcn_global_load_lds(
          (const GAS void*)(Kh + (sup * 128 + kr) * EMBED + cg * 8),
          (LAS void*)(&lK[buf][cb * 8]), 16, 0, 0);
    }
  };

  stage(0, 0);
  for (int sup = 0; sup < SEQ / 128; ++sup) {
    const int cur = sup & 1;
    __syncthreads();  // drains stage(sup); guards buffer reuse
    // vf half 1 issued BEFORE the next stage: consuming an older load never
    // waits younger ones, so PV half 1 won't wait on the staging loads.
    bf16x8 vf0[4];
#pragma unroll
    for (int es = 0; es < 4; ++es)
      vf0[es] = *(const bf16x8*)(Vfh + (((sup * 4 + wk) * 8 + es) * 64 + l) * 8);
    if (sup + 1 < SEQ / 128) stage(sup + 1, cur ^ 1);
    const u16* Kb = lK[cur];
    // ---- S^T = K . Q^T per 16-key tile ns; kf read once each ----
#pragma unroll
    for (int ns = 0; ns < 2; ++ns) {
      f32x4 sacc[4] = {};
#pragma unroll
      for (int kc = 0; kc < 4; ++kc) {
        int kr = wk * 32 + ns * 16 + ln;
        bf16x8 kf = *(const bf16x8*)(Kb + kr * 128 + (((kc * 4 + quad) ^ ln) * 8));
#pragma unroll
        for (int rs = 0; rs < 4; ++rs)
          sacc[rs] = __builtin_amdgcn_mfma_f32_16x16x32_bf16(kf, qf[rs][kc],
                                                             sacc[rs], 0, 0, 0);
      }
      // lane holds S[qrow = rs*16+ln][keys wk*32+ns*16+quad*4 .. +3]
#pragma unroll
      for (int rs = 0; rs < 4; ++rs) {
        u16x4 pk;
        pk.x = f2b(exp2f(sacc[rs][0]));
        pk.y = f2b(exp2f(sacc[rs][1]));
        pk.z = f2b(exp2f(sacc[rs][2]));
        pk.w = f2b(exp2f(sacc[rs][3]));
        *(u16x4*)(Pw + (rs * 16 + ln) * 32 + ((ns * 4 + quad) ^ (ln & 7)) * 4) = pk;
      }
    }
    // ---- pa (A-frag of P) from Pw: two b64 halves per rs ----
    bf16x8 pa[4];
#pragma unroll
    for (int rs = 0; rs < 4; ++rs) {
      u16x4 lo = *(const u16x4*)(Pw + (rs * 16 + ln) * 32 + ((2 * quad) ^ (ln & 7)) * 4);
      u16x4 hi = *(const u16x4*)(Pw + (rs * 16 + ln) * 32 + ((2 * quad + 1) ^ (ln & 7)) * 4);
      u16x8 cc = {lo.x, lo.y, lo.z, lo.w, hi.x, hi.y, hi.z, hi.w};
      pa[rs] = __builtin_bit_cast(bf16x8, cc);
    }
    // vf half 2 in flight during PV half 1
    bf16x8 vf1[4];
#pragma unroll
    for (int es = 0; es < 4; ++es)
      vf1[es] = *(const bf16x8*)(Vfh + (((sup * 4 + wk) * 8 + es + 4) * 64 + l) * 8);
#pragma unroll
    for (int es = 0; es < 4; ++es)
#pragma unroll
      for (int rs = 0; rs < 4; ++rs)
        oacc[rs][es] = __builtin_amdgcn_mfma_f32_16x16x32_bf16(pa[rs], vf0[es],
                                                               oacc[rs][es], 0, 0, 0);
#pragma unroll
    for (int es = 0; es < 4; ++es)
#pragma unroll
      for (int rs = 0; rs < 4; ++rs)
        oacc[rs][es + 4] = __builtin_amdgcn_mfma_f32_16x16x32_bf16(pa[rs], vf1[es],
                                                                   oacc[rs][es + 4], 0, 0, 0);
#pragma unroll
    for (int rs = 0; rs < 4; ++rs)
      lacc[rs] = __builtin_amdgcn_mfma_f32_16x16x32_bf16(pa[rs], onesf, lacc[rs], 0, 0, 0);
  }
  // ---- sequential merge of the 4 key-split partials (no-max softmax:
  //      O = sum O_wk, l = sum l_wk), then normalize + store ----
  __syncthreads();
  float* lO = (float*)&lK[0][0];  // 64 x 128 fp32 = 32 KB
  float* lL = (float*)&lK[1][0];  // 64 fp32
  for (int st = 3; st >= 1; --st) {
    if (wk == st) {
#pragma unroll
      for (int rs = 0; rs < 4; ++rs) {
#pragma unroll
        for (int es = 0; es < 8; ++es)
#pragma unroll
          for (int r = 0; r < 4; ++r) {
            int idx = (rs * 16 + quad * 4 + r) * 128 + es * 16 + ln;
            if (st == 3) lO[idx] = oacc[rs][es][r];
            else lO[idx] += oacc[rs][es][r];
          }
        if (ln == 0)
#pragma unroll
          for (int r = 0; r < 4; ++r) {
            int row = rs * 16 + quad * 4 + r;
            if (st == 3) lL[row] = lacc[rs][r];
            else lL[row] += lacc[rs][r];
          }
      }
    }
    __syncthreads();
  }
  if (wk == 0) {
#pragma unroll
    for (int rs = 0; rs < 4; ++rs)
#pragma unroll
      for (int r = 0; r < 4; ++r) {
        int row = rs * 16 + quad * 4 + r;
        float lsum = __shfl(lacc[rs][r], l & 48) + lL[row];
        float rl = 1.f / lsum;
        int srow = qb * 64 + row;
#pragma unroll
        for (int es = 0; es < 8; ++es) {
          float o = oacc[rs][es][r] + lO[row * 128 + es * 16 + ln];
          Zs[(long)srow * (NHEAD * EMBED) + h * EMBED + es * 16 + ln] = f2b(o * rl);
        }
      }
  }
}

// ---------------- out = Zs · proj, split-K=8 into partials ----------------
__global__ __launch_bounds__(256, 2) void final_gemm_kernel(const u16* __restrict__ Zs,
                                                            const u16* __restrict__ projT,
                                                            float* __restrict__ pbuf) {
  const int t = blockIdx.x;
  const int kc = blockIdx.y;
  gemm128<0>(Zs + (long)t * 128 * (NHEAD * EMBED) + kc * 256, projT + kc * 256,
             pbuf + (long)kc * SEQ * EMBED + t * 128 * EMBED,
             NHEAD * EMBED, NHEAD * EMBED, EMBED, 4, nullptr, nullptr, 1.f, 0, 0);
}

__global__ __launch_bounds__(256) void reduce_kernel(const float* __restrict__ pbuf,
                                                     float* __restrict__ out) {
  int i = (blockIdx.x * 256 + threadIdx.x) * 4;
  float4 s = {0.f, 0.f, 0.f, 0.f};
#pragma unroll
  for (int kc = 0; kc < 8; ++kc) {
    float4 v = *(const float4*)(pbuf + (long)kc * SEQ * EMBED + i);
    s.x += v.x; s.y += v.y; s.z += v.z; s.w += v.w;
  }
  *(float4*)(out + i) = s;
}

extern "C" void kernel_launch(void* const* d_in, const int* in_sizes, int n_in,
                              void* d_out, int out_size, void* d_ws, size_t ws_size,
                              hipStream_t stream) {
  const float* x    = (const float*)d_in[0];
  const float* Wq   = (const float*)d_in[1];
  const float* bq   = (const float*)d_in[2];
  const float* Wk   = (const float*)d_in[3];
  const float* bk   = (const float*)d_in[4];
  const float* Wv   = (const float*)d_in[5];
  const float* bv   = (const float*)d_in[6];
  const float* proj = (const float*)d_in[7];
  float* out = (float*)d_out;

  char* ws = (char*)d_ws;
  u16* xb    = (u16*)(ws);                      // 2048x1024 bf16       (4 MiB)
  u16* Wqt   = (u16*)(ws + (4L << 20));         // [16][128][1024]      (4 MiB)
  u16* Wkt   = (u16*)(ws + (8L << 20));         //                      (4 MiB)
  u16* Wvt   = (u16*)(ws + (12L << 20));        //                      (4 MiB)
  u16* projT = (u16*)(ws + (16L << 20));        // [128][2048]          (0.5 MiB)
  u16* Qf    = (u16*)(ws + (17L << 20));        // Q fragment-major     (8 MiB)
  u16* Km    = (u16*)(ws + (26L << 20));        // [16][2048][128]      (8 MiB)
  u16* Vf    = (u16*)(ws + (35L << 20));        // V fragment-major     (8 MiB)
  u16* Zs    = (u16*)(ws + (44L << 20));        // [2048][2048]         (8 MiB)
  float* pbuf = (float*)(ws);                   // [8][2048][128] fp32  (8 MiB, aliased)

  cast_x_kernel<<<dim3(SEQ * WORD / 1024), dim3(256), 0, stream>>>(x, xb);
  transpose_cast_kernel<<<dim3(WORD / 32, EMBED / 32, 48), dim3(256), 0, stream>>>(
      Wq, Wk, Wv, Wqt, Wkt, Wvt, WORD, EMBED, (long)WORD * EMBED, 1);
  transpose_cast_kernel<<<dim3(SEQ / 32, EMBED / 32, 1), dim3(256), 0, stream>>>(
      proj, nullptr, nullptr, projT, nullptr, nullptr, SEQ, EMBED, 0, 0);

  qkv_gemm_kernel<<<dim3(16, NHEAD, 3), dim3(256), 0, stream>>>(
      xb, Wqt, Wkt, Wvt, bq, bk, bv, Qf, Km, Vf);

  attn_kernel<<<dim3(32, NHEAD), dim3(256), 0, stream>>>(Qf, Km, Vf, Zs);

  final_gemm_kernel<<<dim3(16, 8), dim3(256), 0, stream>>>(Zs, projT, pbuf);
  reduce_kernel<<<dim3(SEQ * EMBED / 1024), dim3(256), 0, stream>>>(pbuf, out);
}

// Round 6
// 208.112 us; speedup vs baseline: 1.3227x; 1.3227x over previous
//
#include <hip/hip_runtime.h>
#include <stdint.h>

#define GAS __attribute__((address_space(1)))
#define LAS __attribute__((address_space(3)))

typedef unsigned short u16;
typedef __attribute__((ext_vector_type(8))) __bf16 bf16x8;
typedef __attribute__((ext_vector_type(4))) float f32x4;
typedef __attribute__((ext_vector_type(4))) unsigned short u16x4;

#define SEQ 2048
#define WORD 1024
#define EMBED 128
#define NHEAD 16

__device__ __forceinline__ u16 f2b(float f) {
  return __builtin_bit_cast(u16, (__bf16)f);
}

// Q fragment-major offset (within one head): lane l of row-tile rt, e-chunk kc
// reads qf = Qf[((rt*4+kc)*64 + l)*8 .. +7]  (qrow = rt*16 + (l&15),
// e = kc*32 + (l>>4)*8 + j)
__device__ __forceinline__ long qfrag_off(int qrow, int e) {
  return ((((long)(qrow >> 4)) * 4 + (e >> 5)) * 64 + ((e >> 3) & 3) * 16 +
          (qrow & 15)) * 8 + (e & 7);
}

// ---------------- cast x (fp32 -> bf16), 4 elems/thread ----------------
__global__ __launch_bounds__(256) void cast_x_kernel(const float* __restrict__ x,
                                                     u16* __restrict__ xb) {
  int i = (blockIdx.x * 256 + threadIdx.x) * 4;
  float4 v = *(const float4*)(x + i);
  ushort4 o;
  o.x = f2b(v.x); o.y = f2b(v.y); o.z = f2b(v.z); o.w = f2b(v.w);
  *(ushort4*)(xb + i) = o;
}

// ------------- transpose+cast: src[R][C] fp32 -> dst[C][R] bf16 --------
__global__ __launch_bounds__(256) void transpose_cast_kernel(
    const float* __restrict__ s0, const float* __restrict__ s1,
    const float* __restrict__ s2, u16* __restrict__ d0, u16* __restrict__ d1,
    u16* __restrict__ d2, int R, int C, long stride, int zsel) {
  __shared__ float tile[32][33];
  const float* s;
  u16* d;
  if (zsel) {
    int z = blockIdx.z;
    int wsel = z >> 4, hh = z & 15;
    s = (wsel == 0 ? s0 : wsel == 1 ? s1 : s2) + (long)hh * stride;
    d = (wsel == 0 ? d0 : wsel == 1 ? d1 : d2) + (long)hh * stride;
  } else {
    s = s0; d = d0;
  }
  int r0 = blockIdx.x * 32, c0 = blockIdx.y * 32;
  int tx = threadIdx.x & 31, ty = threadIdx.x >> 5;
#pragma unroll
  for (int i = 0; i < 4; ++i)
    tile[ty + i * 8][tx] = s[(long)(r0 + ty + i * 8) * C + c0 + tx];
  __syncthreads();
#pragma unroll
  for (int i = 0; i < 4; ++i)
    d[(long)(c0 + ty + i * 8) * R + r0 + tx] = f2b(tile[tx][ty + i * 8]);
}

// ---------------- generic 128x128-tile GEMM: C = (A·B^T + bias) * scale ----
// MODE: 0 = fp32 linear, 1 = u16 linear, 2 = u16 Q-fragment-major.
template <int MODE>
__device__ __forceinline__ void gemm128(const u16* __restrict__ A, const u16* __restrict__ B,
                                        void* __restrict__ Cp, int lda, int ldb, int ldc,
                                        int ksteps, const float* biasN, const float* biasM,
                                        float scale, int rowbase) {
  __shared__ u16 lA[128 * 64];
  __shared__ u16 lB[128 * 64];
  const int tid = threadIdx.x;
  const int l = tid & 63, w = tid >> 6;
  const int quad = l >> 4, ln = l & 15;
  const int wm = w >> 1, wn = w & 1;
  f32x4 acc[4][4] = {};
  for (int ks = 0; ks < ksteps; ++ks) {
    const u16* Ak = A + ks * 64;
    const u16* Bk = B + ks * 64;
    __syncthreads();
#pragma unroll
    for (int i = 0; i < 4; ++i) {
      int idx = w * 256 + i * 64 + l;
      int r = idx >> 3, cp = idx & 7;
      int cg = cp ^ (r & 7);
      __builtin_amdgcn_global_load_lds((const GAS void*)(Ak + (long)r * lda + cg * 8),
                                       (LAS void*)(lA + (w * 256 + i * 64) * 8), 16, 0, 0);
      __builtin_amdgcn_global_load_lds((const GAS void*)(Bk + (long)r * ldb + cg * 8),
                                       (LAS void*)(lB + (w * 256 + i * 64) * 8), 16, 0, 0);
    }
    __syncthreads();
    bf16x8 af[2][4], bfv[2][4];
#pragma unroll
    for (int kc = 0; kc < 2; ++kc) {
#pragma unroll
      for (int i = 0; i < 4; ++i) {
        int c = kc * 4 + quad;
        int rm = wm * 64 + i * 16 + ln;
        af[kc][i] = *(const bf16x8*)(lA + rm * 64 + ((c ^ (rm & 7)) * 8));
        int rn = wn * 64 + i * 16 + ln;
        bfv[kc][i] = *(const bf16x8*)(lB + rn * 64 + ((c ^ (rn & 7)) * 8));
      }
    }
#pragma unroll
    for (int kc = 0; kc < 2; ++kc)
#pragma unroll
      for (int i = 0; i < 4; ++i)
#pragma unroll
        for (int j = 0; j < 4; ++j)
          acc[i][j] = __builtin_amdgcn_mfma_f32_16x16x32_bf16(af[kc][i], bfv[kc][j],
                                                              acc[i][j], 0, 0, 0);
  }
#pragma unroll
  for (int i = 0; i < 4; ++i) {
#pragma unroll
    for (int j = 0; j < 4; ++j) {
      int row0 = wm * 64 + i * 16 + quad * 4;
      int col = wn * 64 + j * 16 + ln;
      float bn = biasN ? biasN[col] : 0.f;
#pragma unroll
      for (int reg = 0; reg < 4; ++reg) {
        int row = row0 + reg;
        float bm = biasM ? biasM[row] : 0.f;
        float v = (acc[i][j][reg] + bn + bm) * scale;
        if constexpr (MODE == 0) {
          ((float*)Cp)[(long)row * ldc + col] = v;
        } else if constexpr (MODE == 1) {
          ((u16*)Cp)[(long)row * ldc + col] = f2b(v);
        } else {
          ((u16*)Cp)[qfrag_off(rowbase + row, col)] = f2b(v);
        }
      }
    }
  }
}

// ---------------- fused QKV projection (z: 0=Q,1=K,2=V^T) ----------------
// Q written fragment-major with log2(e)/sqrt(E) folded in.
__global__ __launch_bounds__(256, 3) void qkv_gemm_kernel(
    const u16* __restrict__ xb, const u16* __restrict__ Wqt, const u16* __restrict__ Wkt,
    const u16* __restrict__ Wvt, const float* __restrict__ bq, const float* __restrict__ bk,
    const float* __restrict__ bv, u16* __restrict__ Qf, u16* __restrict__ Km,
    u16* __restrict__ Vt) {
  const int t = blockIdx.x;
  const int h = blockIdx.y;
  const int which = blockIdx.z;
  const float qscale = 0.12753042123789493f;  // log2(e)/sqrt(128)
  if (which == 0) {
    gemm128<2>(xb + t * 128 * WORD, Wqt + h * EMBED * WORD,
               Qf + (long)h * 262144, WORD, WORD, 0,
               WORD / 64, bq + h * EMBED, nullptr, qscale, t * 128);
  } else if (which == 1) {
    gemm128<1>(xb + t * 128 * WORD, Wkt + h * EMBED * WORD,
               Km + (long)h * SEQ * EMBED + t * 128 * EMBED, WORD, WORD, EMBED,
               WORD / 64, bk + h * EMBED, nullptr, 1.f, 0);
  } else {
    // V^T[e][s] = sum_w Wvt[h][e][w] * x[s][w]  (A=Wvt rows e, B=x rows s)
    gemm128<1>(Wvt + h * EMBED * WORD, xb + t * 128 * WORD,
               Vt + (long)h * EMBED * SEQ + t * 128, WORD, WORD, SEQ,
               WORD / 64, nullptr, bv + h * EMBED, 1.f, 0);
  }
}

// ---------------- flash attention, no-max softmax, S^T form ----------------
// r3 skeleton (proven best) + 3 fixes. Block = 256 thr = (2 row-groups wr of
// 32 q rows) x (2 key-groups wk); grid 32x16 = 512 blocks; LDS 74 KB -> 2
// blocks/CU = 8 waves/CU. Superiter = 64 keys, K+V double-buffered, ONE
// barrier per sup with prefetch issued right after it: compute touches only
// LDS/registers (Q persistent, V staged) => zero vmcnt waits in the compute
// phase; staging has the full compute phase to land.
// S^T = K.Q^T (A/B fragment byte-layouts are identical, m89): lane gets 4
// consecutive keys -> P via ds_write_b64 (packed cvt) + ds_read_b128, row
// stride 40 u16 (80 B: 16B-aligned b128, worst 2-way bank aliasing = free).
__global__ __launch_bounds__(256, 2) void attn_kernel(const u16* __restrict__ Qf,
                                                      const u16* __restrict__ Km,
                                                      const u16* __restrict__ Vt,
                                                      u16* __restrict__ Zs) {
  __shared__ u16 lKV[2][2][8192];  // [buf][K|V]: K 64keys x 128e, V 128e x 64keys
  __shared__ u16 lP[4][32 * 40];   // per-wave P [32 qrows][32 keys], stride 40
  const int h = blockIdx.y, qb = blockIdx.x;  // qb: 64-row q tile, 0..31
  const int tid = threadIdx.x;
  const int l = tid & 63, w = tid >> 6, quad = l >> 4, ln = l & 15;
  const int wr = w >> 1, wk = w & 1;
  const u16* Kh = Km + (long)h * SEQ * EMBED;
  const u16* Vh = Vt + (long)h * EMBED * SEQ;
  const u16* Qfh = Qf + (long)h * 262144;
  u16* Pw = lP[w];

  // persistent Q fragments (coalesced fragment-major loads, once); these are
  // B-operands for S^T = K.Q^T (same bytes as the A-layout, m89)
  bf16x8 qf[2][4];
#pragma unroll
  for (int rs = 0; rs < 2; ++rs)
#pragma unroll
    for (int kc = 0; kc < 4; ++kc)
      qf[rs][kc] = *(const bf16x8*)(Qfh + (((qb * 4 + wr * 2 + rs) * 4 + kc) * 64 + l) * 8);

  const __bf16 ov = (ln == 0) ? (__bf16)1.0f : (__bf16)0.0f;
  const bf16x8 onesf = {ov, ov, ov, ov, ov, ov, ov, ov};

  f32x4 oacc[2][8] = {};
  f32x4 lacc[2] = {};

  // stage 64 keys of K and V into buffer `buf` (8 issues/thread)
  auto stage = [&](int sup, int buf) {
#pragma unroll
    for (int j = 0; j < 4; ++j) {
      int ck = j * 256 + w * 64 + l;               // K chunk 0..1023
      int kr = ck >> 4, cg = (ck & 15) ^ (kr & 15);
      __builtin_amdgcn_global_load_lds(
          (const GAS void*)(Kh + (sup * 64 + kr) * EMBED + cg * 8),
          (LAS void*)(&lKV[buf][0][(j * 256 + w * 64) * 8]), 16, 0, 0);
      int cv = j * 256 + w * 64 + l;               // V chunk 0..1023
      int rv = cv >> 3, cgv = (cv & 7) ^ (rv & 7);
      __builtin_amdgcn_global_load_lds(
          (const GAS void*)(Vh + (long)rv * SEQ + sup * 64 + cgv * 8),
          (LAS void*)(&lKV[buf][1][(j * 256 + w * 64) * 8]), 16, 0, 0);
    }
  };

  stage(0, 0);
  for (int sup = 0; sup < SEQ / 64; ++sup) {
    const int cur = sup & 1;
    __syncthreads();  // drains stage(sup) (vmcnt0) + all DS retired -> safe reuse
    if (sup + 1 < SEQ / 64) stage(sup + 1, cur ^ 1);
    const u16* Kb = lKV[cur][0];
    const u16* Vb = lKV[cur][1];
    // ---- S^T = K.Q^T over this wave's 32 keys (2 ns-tiles) ----
#pragma unroll
    for (int ns = 0; ns < 2; ++ns) {
      f32x4 sacc[2] = {};
#pragma unroll
      for (int kc = 0; kc < 4; ++kc) {
        int ks = wk * 32 + ns * 16 + ln;  // key row in 64-key buffer
        bf16x8 kf = *(const bf16x8*)(Kb + ks * 128 + (((kc * 4 + quad) ^ (ks & 15)) * 8));
#pragma unroll
        for (int rs = 0; rs < 2; ++rs)
          sacc[rs] = __builtin_amdgcn_mfma_f32_16x16x32_bf16(kf, qf[rs][kc],
                                                             sacc[rs], 0, 0, 0);
      }
      // lane: qrow = rs*16+ln, keys(local) = ns*16+quad*4 .. +3 -> one b64
#pragma unroll
      for (int rs = 0; rs < 2; ++rs) {
        u16x4 pk;
        pk.x = f2b(exp2f(sacc[rs][0]));
        pk.y = f2b(exp2f(sacc[rs][1]));
        pk.z = f2b(exp2f(sacc[rs][2]));
        pk.w = f2b(exp2f(sacc[rs][3]));
        *(u16x4*)(Pw + (rs * 16 + ln) * 40 + (ns * 4 + quad) * 4) = pk;
      }
    }
    // ---- pa: A-frag of P (m=qrow=ln, k=key=quad*8+j), aligned b128 ----
    bf16x8 pa[2];
#pragma unroll
    for (int rs = 0; rs < 2; ++rs)
      pa[rs] = *(const bf16x8*)(Pw + (rs * 16 + ln) * 40 + quad * 8);
    // ---- vf: B-frags of V (n=e row, k = wave's 32 keys) ----
    bf16x8 vf[8];
#pragma unroll
    for (int es = 0; es < 8; ++es) {
      int er = es * 16 + ln;
      vf[es] = *(const bf16x8*)(Vb + er * 64 + (((wk * 4 + quad) ^ (er & 7)) * 8));
    }
    // ---- O += P.V ; l += P.ones ----
#pragma unroll
    for (int es = 0; es < 8; ++es)
#pragma unroll
      for (int rs = 0; rs < 2; ++rs)
        oacc[rs][es] = __builtin_amdgcn_mfma_f32_16x16x32_bf16(pa[rs], vf[es],
                                                               oacc[rs][es], 0, 0, 0);
#pragma unroll
    for (int rs = 0; rs < 2; ++rs)
      lacc[rs] = __builtin_amdgcn_mfma_f32_16x16x32_bf16(pa[rs], onesf, lacc[rs], 0, 0, 0);
  }
  // ---- merge wk=1 into wk=0 via LDS (reuses lKV), divide by l, store ----
  __syncthreads();
  float* lO = (float*)lKV;        // 64 x 132 fp32 = 33.8 KB
  float* lL = lO + 64 * 132;      // 64 fp32
  if (wk == 1) {
#pragma unroll
    for (int rs = 0; rs < 2; ++rs) {
#pragma unroll
      for (int es = 0; es < 8; ++es)
#pragma unroll
        for (int r = 0; r < 4; ++r)
          lO[(wr * 32 + rs * 16 + quad * 4 + r) * 132 + es * 16 + ln] = oacc[rs][es][r];
      if (ln == 0)
#pragma unroll
        for (int r = 0; r < 4; ++r)
          lL[wr * 32 + rs * 16 + quad * 4 + r] = lacc[rs][r];
    }
  }
  __syncthreads();
  if (wk == 0) {
#pragma unroll
    for (int rs = 0; rs < 2; ++rs)
#pragma unroll
      for (int r = 0; r < 4; ++r) {
        int grow = wr * 32 + rs * 16 + quad * 4 + r;
        float lsum = __shfl(lacc[rs][r], l & 48) + lL[grow];
        float rl = 1.f / lsum;
        int srow = qb * 64 + grow;
#pragma unroll
        for (int es = 0; es < 8; ++es) {
          float o = oacc[rs][es][r] + lO[grow * 132 + es * 16 + ln];
          Zs[(long)srow * (NHEAD * EMBED) + h * EMBED + es * 16 + ln] = f2b(o * rl);
        }
      }
  }
}

// ---------------- out = Zs · proj, split-K=8 into partials ----------------
__global__ __launch_bounds__(256, 2) void final_gemm_kernel(const u16* __restrict__ Zs,
                                                            const u16* __restrict__ projT,
                                                            float* __restrict__ pbuf) {
  const int t = blockIdx.x;
  const int kc = blockIdx.y;
  gemm128<0>(Zs + (long)t * 128 * (NHEAD * EMBED) + kc * 256, projT + kc * 256,
             pbuf + (long)kc * SEQ * EMBED + t * 128 * EMBED,
             NHEAD * EMBED, NHEAD * EMBED, EMBED, 4, nullptr, nullptr, 1.f, 0);
}

__global__ __launch_bounds__(256) void reduce_kernel(const float* __restrict__ pbuf,
                                                     float* __restrict__ out) {
  int i = (blockIdx.x * 256 + threadIdx.x) * 4;
  float4 s = {0.f, 0.f, 0.f, 0.f};
#pragma unroll
  for (int kc = 0; kc < 8; ++kc) {
    float4 v = *(const float4*)(pbuf + (long)kc * SEQ * EMBED + i);
    s.x += v.x; s.y += v.y; s.z += v.z; s.w += v.w;
  }
  *(float4*)(out + i) = s;
}

extern "C" void kernel_launch(void* const* d_in, const int* in_sizes, int n_in,
                              void* d_out, int out_size, void* d_ws, size_t ws_size,
                              hipStream_t stream) {
  const float* x    = (const float*)d_in[0];
  const float* Wq   = (const float*)d_in[1];
  const float* bq   = (const float*)d_in[2];
  const float* Wk   = (const float*)d_in[3];
  const float* bk   = (const float*)d_in[4];
  const float* Wv   = (const float*)d_in[5];
  const float* bv   = (const float*)d_in[6];
  const float* proj = (const float*)d_in[7];
  float* out = (float*)d_out;

  char* ws = (char*)d_ws;
  u16* xb    = (u16*)(ws);                      // 2048x1024 bf16       (4 MiB)
  u16* Wqt   = (u16*)(ws + (4L << 20));         // [16][128][1024]      (4 MiB)
  u16* Wkt   = (u16*)(ws + (8L << 20));         //                      (4 MiB)
  u16* Wvt   = (u16*)(ws + (12L << 20));        //                      (4 MiB)
  u16* projT = (u16*)(ws + (16L << 20));        // [128][2048]          (0.5 MiB)
  u16* Qf    = (u16*)(ws + (17L << 20));        // Q fragment-major     (8 MiB)
  u16* Km    = (u16*)(ws + (26L << 20));        // [16][2048][128]      (8 MiB)
  u16* Vt    = (u16*)(ws + (35L << 20));        // [16][128][2048]      (8 MiB)
  u16* Zs    = (u16*)(ws + (44L << 20));        // [2048][2048]         (8 MiB)
  float* pbuf = (float*)(ws);                   // [8][2048][128] fp32  (8 MiB, aliased)

  cast_x_kernel<<<dim3(SEQ * WORD / 1024), dim3(256), 0, stream>>>(x, xb);
  transpose_cast_kernel<<<dim3(WORD / 32, EMBED / 32, 48), dim3(256), 0, stream>>>(
      Wq, Wk, Wv, Wqt, Wkt, Wvt, WORD, EMBED, (long)WORD * EMBED, 1);
  transpose_cast_kernel<<<dim3(SEQ / 32, EMBED / 32, 1), dim3(256), 0, stream>>>(
      proj, nullptr, nullptr, projT, nullptr, nullptr, SEQ, EMBED, 0, 0);

  qkv_gemm_kernel<<<dim3(16, NHEAD, 3), dim3(256), 0, stream>>>(
      xb, Wqt, Wkt, Wvt, bq, bk, bv, Qf, Km, Vt);

  attn_kernel<<<dim3(32, NHEAD), dim3(256), 0, stream>>>(Qf, Km, Vt, Zs);

  final_gemm_kernel<<<dim3(16, 8), dim3(256), 0, stream>>>(Zs, projT, pbuf);
  reduce_kernel<<<dim3(SEQ * EMBED / 1024), dim3(256), 0, stream>>>(pbuf, out);
}